// Round 11
// baseline (78.355 us; speedup 1.0000x reference)
//
#include <hip/hip_runtime.h>
#include <hip/hip_bf16.h>

// GCN layer: out = A_hat @ (x @ W) + bias,  A_hat = D^-1/2 (A+I) D^-1/2.
// N=50000, E=600000, IN=128, OUT=64.
//
// Algebra: z[j] = isd[j]*(x[j]@W)  =>  out[i] = isd[i]*(sum_adj z[j] + z[i]) + b
// so the gather needs NO per-edge coefficients (no scattered cnt loads, no
// rsqrt, no cf shfls) - pure row adds with a 2-round dependency chain.
//
// Pipeline (4 kernels):
//   1) zero_cnt
//   2) fill_bucket: edges bucketed by dst via int atomics (CAP=64), int2 loads
//   3) gemm: z = isd*(x@W) bf16 (reads cnt for isd); writes zero row z[n]
//      for the gather's tail slots. W in LDS; x same-address wave broadcast;
//      named float4 regs only (address-taken arrays => scratch, round 3!).
//   4) gather: s = lane<deg ? bucket : n (zero row); prologue loads all
//      independent; inner loop = 8 z-row loads + adds; out = isd*sum + bias.
//
// NOTE: "fillBufferAligned 256MB" profile rows are the HARNESS poisoning
// d_ws between rocprof replays - not in the timed pipeline.
// NOTE: cooperative mega-kernel (round 9) silently failed to launch - avoid.
// NOTE: nontemporal hints cost +13us (round 8) - avoid.
//
// ws: [cnt: N int][z: (N+1)*64 ushort(bf16)][bucket: N*64 int]

#define IN_CH 128
#define OUT_CH 64
#define CAP 64   // max in-degree; Poisson(12) -> P(deg>63) ~ 1e-30

__global__ void zero_cnt_kernel(int* __restrict__ cnt, int n) {
    int i = blockIdx.x * blockDim.x + threadIdx.x;
    if (i < n) cnt[i] = 0;
}

__global__ void fill_bucket_kernel(const int* __restrict__ ei, int* __restrict__ cnt,
                                   int* __restrict__ bucket, int nE) {
    int p = blockIdx.x * blockDim.x + threadIdx.x;   // edge pair index
    int e0 = p * 2;
    if (e0 >= nE) return;
    int2 s2 = reinterpret_cast<const int2*>(ei)[p];
    int2 d2 = reinterpret_cast<const int2*>(ei + nE)[p];
    int pos0 = atomicAdd(&cnt[d2.x], 1);
    if (pos0 < CAP) bucket[(size_t)d2.x * CAP + pos0] = s2.x;
    if (e0 + 1 < nE) {
        int pos1 = atomicAdd(&cnt[d2.y], 1);
        if (pos1 < CAP) bucket[(size_t)d2.y * CAP + pos1] = s2.y;
    }
}

__device__ __forceinline__ unsigned short f2bf(float f) {
    unsigned int u = __float_as_uint(f);
    unsigned int r = (u + 0x7fffu + ((u >> 16) & 1u)) >> 16;  // RTN-even
    return (unsigned short)r;
}

// z[node][64](bf16) = isd[node] * (x[node][128] @ w[128][64]); z[n][:] = 0.
// 256 threads, 64 nodes/block, grid covers n+1 rows (row n = zero row).
#define NPB 64
#define FMA4(A, xs, Wv) \
    A.x = fmaf(xs, Wv.x, A.x); A.y = fmaf(xs, Wv.y, A.y); \
    A.z = fmaf(xs, Wv.z, A.z); A.w = fmaf(xs, Wv.w, A.w);

__global__ __launch_bounds__(256) void gemm_xw_kernel(const float* __restrict__ x,
                                                      const float* __restrict__ w,
                                                      const int* __restrict__ cnt,
                                                      unsigned short* __restrict__ z, int n) {
    __shared__ float wl[IN_CH * OUT_CH];   // 32 KB
    const int t = threadIdx.x;
    const int base = blockIdx.x * NPB;

    {
        const float4* w4 = reinterpret_cast<const float4*>(w);
        float4* wl4 = reinterpret_cast<float4*>(wl);
        #pragma unroll
        for (int i = 0; i < 8; ++i) wl4[t + i * 256] = w4[t + i * 256];
    }
    __syncthreads();

    const int nq = t >> 4;
    const int cq = t & 15;
    const int n0 = base + nq * 4;
    const int c0 = cq * 4;

    const float4* xr0 = reinterpret_cast<const float4*>(x + (size_t)min(n0 + 0, n - 1) * IN_CH);
    const float4* xr1 = reinterpret_cast<const float4*>(x + (size_t)min(n0 + 1, n - 1) * IN_CH);
    const float4* xr2 = reinterpret_cast<const float4*>(x + (size_t)min(n0 + 2, n - 1) * IN_CH);
    const float4* xr3 = reinterpret_cast<const float4*>(x + (size_t)min(n0 + 3, n - 1) * IN_CH);

    // isd per node (same-address broadcast across the 16 cq lanes); issued
    // early so latency hides under the FMA loop.
    const float is0 = rsqrtf((float)cnt[min(n0 + 0, n - 1)] + 1.0f);
    const float is1 = rsqrtf((float)cnt[min(n0 + 1, n - 1)] + 1.0f);
    const float is2 = rsqrtf((float)cnt[min(n0 + 2, n - 1)] + 1.0f);
    const float is3 = rsqrtf((float)cnt[min(n0 + 3, n - 1)] + 1.0f);

    float4 A0 = make_float4(0.f, 0.f, 0.f, 0.f);
    float4 A1 = A0, A2 = A0, A3 = A0;

    #pragma unroll 8
    for (int k4 = 0; k4 < IN_CH / 4; ++k4) {
        const float4 X0 = xr0[k4];
        const float4 X1 = xr1[k4];
        const float4 X2 = xr2[k4];
        const float4 X3 = xr3[k4];
        const float4 W0 = *reinterpret_cast<const float4*>(&wl[(k4 * 4 + 0) * OUT_CH + c0]);
        const float4 W1 = *reinterpret_cast<const float4*>(&wl[(k4 * 4 + 1) * OUT_CH + c0]);
        const float4 W2 = *reinterpret_cast<const float4*>(&wl[(k4 * 4 + 2) * OUT_CH + c0]);
        const float4 W3 = *reinterpret_cast<const float4*>(&wl[(k4 * 4 + 3) * OUT_CH + c0]);
        FMA4(A0, X0.x, W0) FMA4(A0, X0.y, W1) FMA4(A0, X0.z, W2) FMA4(A0, X0.w, W3)
        FMA4(A1, X1.x, W0) FMA4(A1, X1.y, W1) FMA4(A1, X1.z, W2) FMA4(A1, X1.w, W3)
        FMA4(A2, X2.x, W0) FMA4(A2, X2.y, W1) FMA4(A2, X2.z, W2) FMA4(A2, X2.w, W3)
        FMA4(A3, X3.x, W0) FMA4(A3, X3.y, W1) FMA4(A3, X3.z, W2) FMA4(A3, X3.w, W3)
    }

    // store z = isd*acc for node < n; store zeros for the zero row (node==n)
    #define STORE_ROW(J, A, IS)                                                        \
        if (n0 + J <= n) {                                                             \
            uint2 pk;                                                                  \
            if (n0 + J < n) {                                                          \
                pk.x = (unsigned int)f2bf(IS * A.x) | ((unsigned int)f2bf(IS * A.y) << 16); \
                pk.y = (unsigned int)f2bf(IS * A.z) | ((unsigned int)f2bf(IS * A.w) << 16); \
            } else { pk.x = 0u; pk.y = 0u; }                                           \
            *reinterpret_cast<uint2*>(&z[(size_t)(n0 + J) * OUT_CH + c0]) = pk;        \
        }
    STORE_ROW(0, A0, is0)
    STORE_ROW(1, A1, is1)
    STORE_ROW(2, A2, is2)
    STORE_ROW(3, A3, is3)
    #undef STORE_ROW
}

// One wave per node, block=128 (32 waves/CU). No per-edge coefficients:
// prologue loads (cnt, bucket row, z-self) are independent; tail slots point
// at zero row z[n] (hot in cache). Inner loop: 8 loads + 16 adds per 16 edges.
__global__ __launch_bounds__(128) void gather_kernel(const int* __restrict__ cnt,
                                                     const int* __restrict__ bucket,
                                                     const unsigned short* __restrict__ z,
                                                     const float* __restrict__ bias,
                                                     float* __restrict__ out, int n) {
    const int wid  = threadIdx.x >> 6;
    const int lane = threadIdx.x & 63;
    const int nid  = blockIdx.x * 2 + wid;
    if (nid >= n) return;
    const int hw = lane >> 5;     // 0/1: which edge of the pair
    const int cp = lane & 31;     // channel-pair index

    // three independent loads issued together
    const int degc = cnt[nid];
    const int s_raw = bucket[(size_t)nid * CAP + lane];
    const unsigned int u_self = reinterpret_cast<const unsigned int*>(z + (size_t)nid * OUT_CH)[cp];

    int deg = degc > CAP ? CAP : degc;
    const float isd_d = rsqrtf((float)degc + 1.0f);
    const int s_l = (lane < deg) ? s_raw : n;   // tail -> zero row

    float ax = 0.f, ay = 0.f;
    if (hw == 0) {   // self term z[nid] counted once (halves summed at the end)
        ax = __uint_as_float(u_self << 16);
        ay = __uint_as_float(u_self & 0xffff0000u);
    }

    for (int k = 0; k < deg; k += 16) {
        int s0 = __shfl(s_l, k + 0 + hw),  s1 = __shfl(s_l, k + 2 + hw);
        int s2 = __shfl(s_l, k + 4 + hw),  s3 = __shfl(s_l, k + 6 + hw);
        int s4 = __shfl(s_l, k + 8 + hw),  s5 = __shfl(s_l, k + 10 + hw);
        int s6 = __shfl(s_l, k + 12 + hw), s7 = __shfl(s_l, k + 14 + hw);
        unsigned int v0 = reinterpret_cast<const unsigned int*>(z + (size_t)s0 * OUT_CH)[cp];
        unsigned int v1 = reinterpret_cast<const unsigned int*>(z + (size_t)s1 * OUT_CH)[cp];
        unsigned int v2 = reinterpret_cast<const unsigned int*>(z + (size_t)s2 * OUT_CH)[cp];
        unsigned int v3 = reinterpret_cast<const unsigned int*>(z + (size_t)s3 * OUT_CH)[cp];
        unsigned int v4 = reinterpret_cast<const unsigned int*>(z + (size_t)s4 * OUT_CH)[cp];
        unsigned int v5 = reinterpret_cast<const unsigned int*>(z + (size_t)s5 * OUT_CH)[cp];
        unsigned int v6 = reinterpret_cast<const unsigned int*>(z + (size_t)s6 * OUT_CH)[cp];
        unsigned int v7 = reinterpret_cast<const unsigned int*>(z + (size_t)s7 * OUT_CH)[cp];
        ax += __uint_as_float(v0 << 16);  ay += __uint_as_float(v0 & 0xffff0000u);
        ax += __uint_as_float(v1 << 16);  ay += __uint_as_float(v1 & 0xffff0000u);
        ax += __uint_as_float(v2 << 16);  ay += __uint_as_float(v2 & 0xffff0000u);
        ax += __uint_as_float(v3 << 16);  ay += __uint_as_float(v3 & 0xffff0000u);
        ax += __uint_as_float(v4 << 16);  ay += __uint_as_float(v4 & 0xffff0000u);
        ax += __uint_as_float(v5 << 16);  ay += __uint_as_float(v5 & 0xffff0000u);
        ax += __uint_as_float(v6 << 16);  ay += __uint_as_float(v6 & 0xffff0000u);
        ax += __uint_as_float(v7 << 16);  ay += __uint_as_float(v7 & 0xffff0000u);
    }

    ax += __shfl_xor(ax, 32);
    ay += __shfl_xor(ay, 32);
    if (hw == 0) {
        float2 b2 = reinterpret_cast<const float2*>(bias)[cp];
        float2 o;
        o.x = fmaf(isd_d, ax, b2.x);
        o.y = fmaf(isd_d, ay, b2.y);
        reinterpret_cast<float2*>(out + (size_t)nid * OUT_CH)[cp] = o;
    }
}

extern "C" void kernel_launch(void* const* d_in, const int* in_sizes, int n_in,
                              void* d_out, int out_size, void* d_ws, size_t ws_size,
                              hipStream_t stream) {
    const float* x    = (const float*)d_in[0];
    const int*   ei   = (const int*)d_in[1];
    const float* w    = (const float*)d_in[2];
    const float* bias = (const float*)d_in[3];
    float* out = (float*)d_out;

    const int n  = in_sizes[0] / IN_CH;   // 50000
    const int nE = in_sizes[1] / 2;       // 600000

    char* p = (char*)d_ws;
    auto align256 = [](size_t v) { return (v + 255) & ~(size_t)255; };
    int*            cnt    = (int*)p;             p += align256((size_t)n * 4);
    unsigned short* z      = (unsigned short*)p;  p += align256((size_t)(n + 1) * OUT_CH * 2);
    int*            bucket = (int*)p;

    // 1) cnt = 0
    zero_cnt_kernel<<<(n + 255) / 256, 256, 0, stream>>>(cnt, n);
    // 2) bucket edges by dst (gives deg)
    {
        int nPairs = (nE + 1) / 2;
        fill_bucket_kernel<<<(nPairs + 255) / 256, 256, 0, stream>>>(ei, cnt, bucket, nE);
    }
    // 3) z = isd * (x @ W), bf16; zero row at z[n]
    gemm_xw_kernel<<<(n + NPB) / NPB, 256, 0, stream>>>(x, w, cnt, z, n);  // covers n+1 rows
    // 4) gather: out = isd * (sum z[adj] + z[self]) + bias
    gather_kernel<<<(n + 1) / 2, 128, 0, stream>>>(cnt, bucket, z, bias, out, n);
}

// Round 12
// 76.773 us; speedup vs baseline: 1.0206x; 1.0206x over previous
//
#include <hip/hip_runtime.h>
#include <hip/hip_bf16.h>

// GCN layer: out = A_hat @ (x @ W) + bias,  A_hat = D^-1/2 (A+I) D^-1/2.
// N=50000, E=600000, IN=128, OUT=64.
//
// Pipeline (3 kernels, round-10 structure = best so far, 75.7us):
//   1) gemm(+zero cnt): y = (x@W) bf16. W in LDS; x same-address wave
//      broadcast; named float4 regs only (address-taken arrays => scratch).
//   2) fill_bucket: edges bucketed by dst via int atomics (CAP=64), int2 loads
//   3) gather v2: lane = (edge-slot:8)x(channel-octet:8). One uint4 load
//      covers 8 bf16 channels of one edge row; a batch of 8 slots = 8 edges
//      per vmem instruction. 3 unconditional batches cover deg<=24 (99.92%
//      of Poisson(12)); rare tail loop for deg>24. Butterfly shfl_xor over
//      edge-slots; lanes eg==0 write float4 x2 (+bias). Coefficients via
//      shfl of per-slot cf (0 for slots>=deg -> contribute nothing, row 0).
//
// NOTE: "fillBufferAligned 256MB" profile rows are the HARNESS poisoning
// d_ws between rocprof replays - not in the timed pipeline.
// NOTE: cooperative launch silently fails (round 9); NT hints cost +13us
// (round 8); extra launches cost ~5us each (rounds 10/11).
//
// ws: [cnt: N int][y: N*64 ushort(bf16)][bucket: N*64 int]

#define IN_CH 128
#define OUT_CH 64
#define CAP 64   // max in-degree; Poisson(12) -> P(deg>63) ~ 1e-30

__global__ void fill_bucket_kernel(const int* __restrict__ ei, int* __restrict__ cnt,
                                   int* __restrict__ bucket, int nE) {
    int p = blockIdx.x * blockDim.x + threadIdx.x;   // edge pair index
    int e0 = p * 2;
    if (e0 >= nE) return;
    int2 s2 = reinterpret_cast<const int2*>(ei)[p];
    int2 d2 = reinterpret_cast<const int2*>(ei + nE)[p];
    int pos0 = atomicAdd(&cnt[d2.x], 1);
    if (pos0 < CAP) bucket[(size_t)d2.x * CAP + pos0] = s2.x;
    if (e0 + 1 < nE) {
        int pos1 = atomicAdd(&cnt[d2.y], 1);
        if (pos1 < CAP) bucket[(size_t)d2.y * CAP + pos1] = s2.y;
    }
}

__device__ __forceinline__ unsigned short f2bf(float f) {
    unsigned int u = __float_as_uint(f);
    unsigned int r = (u + 0x7fffu + ((u >> 16) & 1u)) >> 16;  // RTN-even
    return (unsigned short)r;
}

// y[n][64](bf16) = x[n][128] @ w[128][64]; also zeroes cnt[block slice].
#define NPB 64
#define FMA4(A, xs, Wv) \
    A.x = fmaf(xs, Wv.x, A.x); A.y = fmaf(xs, Wv.y, A.y); \
    A.z = fmaf(xs, Wv.z, A.z); A.w = fmaf(xs, Wv.w, A.w);

__global__ __launch_bounds__(256) void gemm_xw_kernel(const float* __restrict__ x,
                                                      const float* __restrict__ w,
                                                      unsigned short* __restrict__ y,
                                                      int* __restrict__ cnt, int n) {
    __shared__ float wl[IN_CH * OUT_CH];   // 32 KB
    const int t = threadIdx.x;
    const int base = blockIdx.x * NPB;

    // side job: zero this block's slice of cnt (fill_bucket runs after us)
    if (t < NPB && base + t < n) cnt[base + t] = 0;

    {
        const float4* w4 = reinterpret_cast<const float4*>(w);
        float4* wl4 = reinterpret_cast<float4*>(wl);
        #pragma unroll
        for (int i = 0; i < 8; ++i) wl4[t + i * 256] = w4[t + i * 256];
    }
    __syncthreads();

    const int nq = t >> 4;
    const int cq = t & 15;
    const int n0 = base + nq * 4;
    const int c0 = cq * 4;

    const float4* xr0 = reinterpret_cast<const float4*>(x + (size_t)min(n0 + 0, n - 1) * IN_CH);
    const float4* xr1 = reinterpret_cast<const float4*>(x + (size_t)min(n0 + 1, n - 1) * IN_CH);
    const float4* xr2 = reinterpret_cast<const float4*>(x + (size_t)min(n0 + 2, n - 1) * IN_CH);
    const float4* xr3 = reinterpret_cast<const float4*>(x + (size_t)min(n0 + 3, n - 1) * IN_CH);

    float4 A0 = make_float4(0.f, 0.f, 0.f, 0.f);
    float4 A1 = A0, A2 = A0, A3 = A0;

    #pragma unroll 8
    for (int k4 = 0; k4 < IN_CH / 4; ++k4) {
        const float4 X0 = xr0[k4];
        const float4 X1 = xr1[k4];
        const float4 X2 = xr2[k4];
        const float4 X3 = xr3[k4];
        const float4 W0 = *reinterpret_cast<const float4*>(&wl[(k4 * 4 + 0) * OUT_CH + c0]);
        const float4 W1 = *reinterpret_cast<const float4*>(&wl[(k4 * 4 + 1) * OUT_CH + c0]);
        const float4 W2 = *reinterpret_cast<const float4*>(&wl[(k4 * 4 + 2) * OUT_CH + c0]);
        const float4 W3 = *reinterpret_cast<const float4*>(&wl[(k4 * 4 + 3) * OUT_CH + c0]);
        FMA4(A0, X0.x, W0) FMA4(A0, X0.y, W1) FMA4(A0, X0.z, W2) FMA4(A0, X0.w, W3)
        FMA4(A1, X1.x, W0) FMA4(A1, X1.y, W1) FMA4(A1, X1.z, W2) FMA4(A1, X1.w, W3)
        FMA4(A2, X2.x, W0) FMA4(A2, X2.y, W1) FMA4(A2, X2.z, W2) FMA4(A2, X2.w, W3)
        FMA4(A3, X3.x, W0) FMA4(A3, X3.y, W1) FMA4(A3, X3.z, W2) FMA4(A3, X3.w, W3)
    }

    #define STORE_ROW(J, A)                                                            \
        if (n0 + J < n) {                                                              \
            uint2 pk;                                                                  \
            pk.x = (unsigned int)f2bf(A.x) | ((unsigned int)f2bf(A.y) << 16);          \
            pk.y = (unsigned int)f2bf(A.z) | ((unsigned int)f2bf(A.w) << 16);          \
            *reinterpret_cast<uint2*>(&y[(size_t)(n0 + J) * OUT_CH + c0]) = pk;        \
        }
    STORE_ROW(0, A0)
    STORE_ROW(1, A1)
    STORE_ROW(2, A2)
    STORE_ROW(3, A3)
    #undef STORE_ROW
}

// gather v2: one wave per node, block=128 (32 waves/CU).
// lane = eg*8 + co: eg = edge slot in batch (8 edges/batch), co = channel
// octet (uint4 = 8 bf16). Per batch: 1 uint4 load per lane = 8 edge rows.
// cf for slot j comes from shfl; slots >= deg carry cf=0, s=0 (hot row 0).
#define ACC8(CF, V)                                                      \
    a0 = fmaf(CF, __uint_as_float((V).x << 16),          a0);            \
    a1 = fmaf(CF, __uint_as_float((V).x & 0xffff0000u),  a1);            \
    a2 = fmaf(CF, __uint_as_float((V).y << 16),          a2);            \
    a3 = fmaf(CF, __uint_as_float((V).y & 0xffff0000u),  a3);            \
    a4 = fmaf(CF, __uint_as_float((V).z << 16),          a4);            \
    a5 = fmaf(CF, __uint_as_float((V).z & 0xffff0000u),  a5);            \
    a6 = fmaf(CF, __uint_as_float((V).w << 16),          a6);            \
    a7 = fmaf(CF, __uint_as_float((V).w & 0xffff0000u),  a7);

#define RED8(M)                                                          \
    a0 += __shfl_xor(a0, M); a1 += __shfl_xor(a1, M);                    \
    a2 += __shfl_xor(a2, M); a3 += __shfl_xor(a3, M);                    \
    a4 += __shfl_xor(a4, M); a5 += __shfl_xor(a5, M);                    \
    a6 += __shfl_xor(a6, M); a7 += __shfl_xor(a7, M);

__global__ __launch_bounds__(128) void gather_kernel(const int* __restrict__ cnt,
                                                     const int* __restrict__ bucket,
                                                     const unsigned short* __restrict__ y,
                                                     const float* __restrict__ bias,
                                                     float* __restrict__ out, int n) {
    const int wid  = threadIdx.x >> 6;
    const int lane = threadIdx.x & 63;
    const int nid  = blockIdx.x * 2 + wid;
    if (nid >= n) return;
    const int eg = lane >> 3;     // 0..7 edge slot within batch
    const int co = lane & 7;      // 0..7 channel octet

    const int degc  = cnt[nid];                            // same-addr broadcast
    const int s_raw = bucket[(size_t)nid * CAP + lane];    // coalesced 256B row
    const int deg   = degc > CAP ? CAP : degc;
    const float isd_d = rsqrtf((float)degc + 1.0f);

    const int s_l = (lane < deg) ? s_raw : 0;              // never deref garbage
    float cf_l = 0.f;
    if (lane < deg) cf_l = isd_d * rsqrtf((float)cnt[s_l] + 1.0f);

    const uint4* z4 = reinterpret_cast<const uint4*>(y);

    float a0 = 0.f, a1 = 0.f, a2 = 0.f, a3 = 0.f,
          a4 = 0.f, a5 = 0.f, a6 = 0.f, a7 = 0.f;

    // self-loop term: row broadcast across eg; only eg==0 applies isd^2
    {
        uint4 vs = z4[(size_t)nid * 8 + co];
        float cs = (eg == 0) ? isd_d * isd_d : 0.f;
        ACC8(cs, vs)
    }

    // 3 unconditional batches: 24 edge slots (covers 99.92% of nodes fully)
    {
        int i0 = __shfl(s_l, 0 + eg), i1 = __shfl(s_l, 8 + eg), i2 = __shfl(s_l, 16 + eg);
        uint4 v0 = z4[(size_t)i0 * 8 + co];
        uint4 v1 = z4[(size_t)i1 * 8 + co];
        uint4 v2 = z4[(size_t)i2 * 8 + co];
        float c0 = __shfl(cf_l, 0 + eg), c1 = __shfl(cf_l, 8 + eg), c2 = __shfl(cf_l, 16 + eg);
        ACC8(c0, v0)
        ACC8(c1, v1)
        ACC8(c2, v2)
    }

    // rare tail (deg > 24): batches of 8
    for (int k = 24; k < deg; k += 8) {
        int   s = __shfl(s_l, k + eg);    // slots >= deg -> s=0, cf=0
        uint4 v = z4[(size_t)s * 8 + co];
        float c = __shfl(cf_l, k + eg);
        ACC8(c, v)
    }

    // reduce across the 8 edge slots (lane bits 3..5)
    RED8(8)
    RED8(16)
    RED8(32)

    if (eg == 0) {
        const float4* b4 = reinterpret_cast<const float4*>(bias);
        float4 blo = b4[co * 2 + 0];
        float4 bhi = b4[co * 2 + 1];
        float4 o0; o0.x = a0 + blo.x; o0.y = a1 + blo.y; o0.z = a2 + blo.z; o0.w = a3 + blo.w;
        float4 o1; o1.x = a4 + bhi.x; o1.y = a5 + bhi.y; o1.z = a6 + bhi.z; o1.w = a7 + bhi.w;
        float4* op = reinterpret_cast<float4*>(out + (size_t)nid * OUT_CH + co * 8);
        op[0] = o0;
        op[1] = o1;
    }
}

extern "C" void kernel_launch(void* const* d_in, const int* in_sizes, int n_in,
                              void* d_out, int out_size, void* d_ws, size_t ws_size,
                              hipStream_t stream) {
    const float* x    = (const float*)d_in[0];
    const int*   ei   = (const int*)d_in[1];
    const float* w    = (const float*)d_in[2];
    const float* bias = (const float*)d_in[3];
    float* out = (float*)d_out;

    const int n  = in_sizes[0] / IN_CH;   // 50000
    const int nE = in_sizes[1] / 2;       // 600000

    char* p = (char*)d_ws;
    auto align256 = [](size_t v) { return (v + 255) & ~(size_t)255; };
    int*            cnt    = (int*)p;             p += align256((size_t)n * 4);
    unsigned short* y      = (unsigned short*)p;  p += align256((size_t)n * OUT_CH * 2);
    int*            bucket = (int*)p;

    // 1) gemm also zeroes cnt (stream order makes it visible to fill_bucket)
    gemm_xw_kernel<<<(n + NPB - 1) / NPB, 256, 0, stream>>>(x, w, y, cnt, n);
    // 2) bucket edges by dst
    {
        int nPairs = (nE + 1) / 2;
        fill_bucket_kernel<<<(nPairs + 255) / 256, 256, 0, stream>>>(ei, cnt, bucket, nE);
    }
    // 3) gather v2
    gather_kernel<<<(n + 1) / 2, 128, 0, stream>>>(cnt, bucket, y, bias, out, n);
}

// Round 13
// 68.488 us; speedup vs baseline: 1.1441x; 1.1210x over previous
//
#include <hip/hip_runtime.h>
#include <hip/hip_bf16.h>

// GCN layer: out = A_hat @ (x @ W) + bias,  A_hat = D^-1/2 (A+I) D^-1/2.
// N=50000, E=600000, IN=128, OUT=64.
//
// Pipeline (3 kernels):
//   1) zero_cnt (tiny)
//   2) MEGA role-split: blocks [0,782) = gemm tiles (y = x@W bf16, W in LDS,
//      x same-address wave broadcast, named float4 regs); blocks [782,1024)
//      = fill_bucket grid-stride (int atomics, CAP=64). gemm and bucket are
//      independent -> bucket's ~6us hides under gemm, one launch+drain gone.
//   3) gather (round-10 best version): one wave/node, 2 bf16 ch per lane,
//      tiered 8/4 loads in flight, wave-uniform branch, block=128.
//
// NOTE: "fillBufferAligned 256MB" profile rows are the HARNESS poisoning
// d_ws between rocprof replays - not in the timed pipeline.
// NOTE: cooperative launch silently fails (round 9); NT hints cost +13us
// (round 8); per-launch overhead ~5-6us (rounds 5/10/11 deltas).
//
// ws: [cnt: N int][y: N*64 ushort(bf16)][bucket: N*64 int]

#define IN_CH 128
#define OUT_CH 64
#define CAP 64        // max in-degree; Poisson(12) -> P(deg>63) ~ 1e-30
#define NPB 64        // gemm nodes per block
#define GEMM_BLOCKS 782   // ceil(50000/64)
#define BUCKET_BLOCKS 242
#define TOTAL_BLOCKS (GEMM_BLOCKS + BUCKET_BLOCKS)

__global__ void zero_cnt_kernel(int* __restrict__ cnt, int n) {
    int i = blockIdx.x * blockDim.x + threadIdx.x;
    if (i < n) cnt[i] = 0;
}

__device__ __forceinline__ unsigned short f2bf(float f) {
    unsigned int u = __float_as_uint(f);
    unsigned int r = (u + 0x7fffu + ((u >> 16) & 1u)) >> 16;  // RTN-even
    return (unsigned short)r;
}

#define FMA4(A, xs, Wv) \
    A.x = fmaf(xs, Wv.x, A.x); A.y = fmaf(xs, Wv.y, A.y); \
    A.z = fmaf(xs, Wv.z, A.z); A.w = fmaf(xs, Wv.w, A.w);

// Role-split mega kernel: gemm blocks + bucket blocks in one dispatch.
__global__ __launch_bounds__(256) void mega_kernel(const float* __restrict__ x,
                                                   const float* __restrict__ w,
                                                   const int* __restrict__ ei,
                                                   unsigned short* __restrict__ y,
                                                   int* __restrict__ cnt,
                                                   int* __restrict__ bucket,
                                                   int n, int nE) {
    __shared__ float wl[IN_CH * OUT_CH];   // 32 KB (used by gemm role only)
    const int t = threadIdx.x;

    if (blockIdx.x >= GEMM_BLOCKS) {
        // ---- bucket role: grid-stride over edge pairs ----
        const int nPairs = (nE + 1) / 2;
        const int stride = BUCKET_BLOCKS * 256;
        for (int p = (blockIdx.x - GEMM_BLOCKS) * 256 + t; p < nPairs; p += stride) {
            int e0 = p * 2;
            int2 s2 = reinterpret_cast<const int2*>(ei)[p];
            int2 d2 = reinterpret_cast<const int2*>(ei + nE)[p];
            int pos0 = atomicAdd(&cnt[d2.x], 1);
            if (pos0 < CAP) bucket[(size_t)d2.x * CAP + pos0] = s2.x;
            if (e0 + 1 < nE) {
                int pos1 = atomicAdd(&cnt[d2.y], 1);
                if (pos1 < CAP) bucket[(size_t)d2.y * CAP + pos1] = s2.y;
            }
        }
        return;
    }

    // ---- gemm role: y[base..base+63][64] = x rows @ W ----
    const int base = blockIdx.x * NPB;
    {
        const float4* w4 = reinterpret_cast<const float4*>(w);
        float4* wl4 = reinterpret_cast<float4*>(wl);
        #pragma unroll
        for (int i = 0; i < 8; ++i) wl4[t + i * 256] = w4[t + i * 256];
    }
    __syncthreads();

    const int nq = t >> 4;
    const int cq = t & 15;
    const int n0 = base + nq * 4;
    const int c0 = cq * 4;

    const float4* xr0 = reinterpret_cast<const float4*>(x + (size_t)min(n0 + 0, n - 1) * IN_CH);
    const float4* xr1 = reinterpret_cast<const float4*>(x + (size_t)min(n0 + 1, n - 1) * IN_CH);
    const float4* xr2 = reinterpret_cast<const float4*>(x + (size_t)min(n0 + 2, n - 1) * IN_CH);
    const float4* xr3 = reinterpret_cast<const float4*>(x + (size_t)min(n0 + 3, n - 1) * IN_CH);

    float4 A0 = make_float4(0.f, 0.f, 0.f, 0.f);
    float4 A1 = A0, A2 = A0, A3 = A0;

    #pragma unroll 8
    for (int k4 = 0; k4 < IN_CH / 4; ++k4) {
        const float4 X0 = xr0[k4];
        const float4 X1 = xr1[k4];
        const float4 X2 = xr2[k4];
        const float4 X3 = xr3[k4];
        const float4 W0 = *reinterpret_cast<const float4*>(&wl[(k4 * 4 + 0) * OUT_CH + c0]);
        const float4 W1 = *reinterpret_cast<const float4*>(&wl[(k4 * 4 + 1) * OUT_CH + c0]);
        const float4 W2 = *reinterpret_cast<const float4*>(&wl[(k4 * 4 + 2) * OUT_CH + c0]);
        const float4 W3 = *reinterpret_cast<const float4*>(&wl[(k4 * 4 + 3) * OUT_CH + c0]);
        FMA4(A0, X0.x, W0) FMA4(A0, X0.y, W1) FMA4(A0, X0.z, W2) FMA4(A0, X0.w, W3)
        FMA4(A1, X1.x, W0) FMA4(A1, X1.y, W1) FMA4(A1, X1.z, W2) FMA4(A1, X1.w, W3)
        FMA4(A2, X2.x, W0) FMA4(A2, X2.y, W1) FMA4(A2, X2.z, W2) FMA4(A2, X2.w, W3)
        FMA4(A3, X3.x, W0) FMA4(A3, X3.y, W1) FMA4(A3, X3.z, W2) FMA4(A3, X3.w, W3)
    }

    #define STORE_ROW(J, A)                                                            \
        if (n0 + J < n) {                                                              \
            uint2 pk;                                                                  \
            pk.x = (unsigned int)f2bf(A.x) | ((unsigned int)f2bf(A.y) << 16);          \
            pk.y = (unsigned int)f2bf(A.z) | ((unsigned int)f2bf(A.w) << 16);          \
            *reinterpret_cast<uint2*>(&y[(size_t)(n0 + J) * OUT_CH + c0]) = pk;        \
        }
    STORE_ROW(0, A0)
    STORE_ROW(1, A1)
    STORE_ROW(2, A2)
    STORE_ROW(3, A3)
    #undef STORE_ROW
}

// Gather (round-10 best): one wave per node, block=128 (32 waves/CU).
// Half-wave hw handles edge k+2i+hw; lane reads one uint (2 bf16 ch) of the
// 128B y row. deg wave-uniform -> tiered non-divergent loop: 8 loads (16
// edges) while >8 remain, else 4 loads. Tail slots: cf=0, s=0 (valid, hot).
#define EDGE_FMA(c, v) \
    ax = fmaf(c, __uint_as_float((v) << 16), ax); \
    ay = fmaf(c, __uint_as_float((v) & 0xffff0000u), ay);

__global__ __launch_bounds__(128) void gather_kernel(const int* __restrict__ cnt,
                                                     const int* __restrict__ bucket,
                                                     const unsigned short* __restrict__ y,
                                                     const float* __restrict__ bias,
                                                     float* __restrict__ out, int n) {
    const int wid  = threadIdx.x >> 6;
    const int lane = threadIdx.x & 63;
    const int nid  = blockIdx.x * 2 + wid;
    if (nid >= n) return;
    const int hw = lane >> 5;
    const int cp = lane & 31;

    int deg = cnt[nid];
    if (deg > CAP) deg = CAP;
    const float isd_d = rsqrtf((float)cnt[nid] + 1.0f);

    int   s_l  = 0;
    float cf_l = 0.f;
    if (lane < deg) {
        s_l  = bucket[(size_t)nid * CAP + lane];
        cf_l = isd_d * rsqrtf((float)cnt[s_l] + 1.0f);
    }

    float ax = 0.f, ay = 0.f;
    if (hw == 0) {
        float2 b2 = reinterpret_cast<const float2*>(bias)[cp];
        unsigned int u = reinterpret_cast<const unsigned int*>(y + (size_t)nid * OUT_CH)[cp];
        float sl = isd_d * isd_d;
        ax = fmaf(sl, __uint_as_float(u << 16), b2.x);
        ay = fmaf(sl, __uint_as_float(u & 0xffff0000u), b2.y);
    }

    for (int k = 0; k < deg; k += 16) {
        int rem = deg - k;
        if (rem > 8) {
            int s0 = __shfl(s_l, k + 0 + hw),  s1 = __shfl(s_l, k + 2 + hw);
            int s2 = __shfl(s_l, k + 4 + hw),  s3 = __shfl(s_l, k + 6 + hw);
            int s4 = __shfl(s_l, k + 8 + hw),  s5 = __shfl(s_l, k + 10 + hw);
            int s6 = __shfl(s_l, k + 12 + hw), s7 = __shfl(s_l, k + 14 + hw);
            unsigned int v0 = reinterpret_cast<const unsigned int*>(y + (size_t)s0 * OUT_CH)[cp];
            unsigned int v1 = reinterpret_cast<const unsigned int*>(y + (size_t)s1 * OUT_CH)[cp];
            unsigned int v2 = reinterpret_cast<const unsigned int*>(y + (size_t)s2 * OUT_CH)[cp];
            unsigned int v3 = reinterpret_cast<const unsigned int*>(y + (size_t)s3 * OUT_CH)[cp];
            unsigned int v4 = reinterpret_cast<const unsigned int*>(y + (size_t)s4 * OUT_CH)[cp];
            unsigned int v5 = reinterpret_cast<const unsigned int*>(y + (size_t)s5 * OUT_CH)[cp];
            unsigned int v6 = reinterpret_cast<const unsigned int*>(y + (size_t)s6 * OUT_CH)[cp];
            unsigned int v7 = reinterpret_cast<const unsigned int*>(y + (size_t)s7 * OUT_CH)[cp];
            float c0 = __shfl(cf_l, k + 0 + hw),  c1 = __shfl(cf_l, k + 2 + hw);
            float c2 = __shfl(cf_l, k + 4 + hw),  c3 = __shfl(cf_l, k + 6 + hw);
            float c4 = __shfl(cf_l, k + 8 + hw),  c5 = __shfl(cf_l, k + 10 + hw);
            float c6 = __shfl(cf_l, k + 12 + hw), c7 = __shfl(cf_l, k + 14 + hw);
            EDGE_FMA(c0, v0) EDGE_FMA(c1, v1) EDGE_FMA(c2, v2) EDGE_FMA(c3, v3)
            EDGE_FMA(c4, v4) EDGE_FMA(c5, v5) EDGE_FMA(c6, v6) EDGE_FMA(c7, v7)
        } else {
            int s0 = __shfl(s_l, k + 0 + hw), s1 = __shfl(s_l, k + 2 + hw);
            int s2 = __shfl(s_l, k + 4 + hw), s3 = __shfl(s_l, k + 6 + hw);
            unsigned int v0 = reinterpret_cast<const unsigned int*>(y + (size_t)s0 * OUT_CH)[cp];
            unsigned int v1 = reinterpret_cast<const unsigned int*>(y + (size_t)s1 * OUT_CH)[cp];
            unsigned int v2 = reinterpret_cast<const unsigned int*>(y + (size_t)s2 * OUT_CH)[cp];
            unsigned int v3 = reinterpret_cast<const unsigned int*>(y + (size_t)s3 * OUT_CH)[cp];
            float c0 = __shfl(cf_l, k + 0 + hw), c1 = __shfl(cf_l, k + 2 + hw);
            float c2 = __shfl(cf_l, k + 4 + hw), c3 = __shfl(cf_l, k + 6 + hw);
            EDGE_FMA(c0, v0) EDGE_FMA(c1, v1) EDGE_FMA(c2, v2) EDGE_FMA(c3, v3)
        }
    }

    ax += __shfl_xor(ax, 32);
    ay += __shfl_xor(ay, 32);
    if (hw == 0) {
        float2 o; o.x = ax; o.y = ay;
        reinterpret_cast<float2*>(out + (size_t)nid * OUT_CH)[cp] = o;
    }
}

extern "C" void kernel_launch(void* const* d_in, const int* in_sizes, int n_in,
                              void* d_out, int out_size, void* d_ws, size_t ws_size,
                              hipStream_t stream) {
    const float* x    = (const float*)d_in[0];
    const int*   ei   = (const int*)d_in[1];
    const float* w    = (const float*)d_in[2];
    const float* bias = (const float*)d_in[3];
    float* out = (float*)d_out;

    const int n  = in_sizes[0] / IN_CH;   // 50000
    const int nE = in_sizes[1] / 2;       // 600000

    char* p = (char*)d_ws;
    auto align256 = [](size_t v) { return (v + 255) & ~(size_t)255; };
    int*            cnt    = (int*)p;             p += align256((size_t)n * 4);
    unsigned short* y      = (unsigned short*)p;  p += align256((size_t)n * OUT_CH * 2);
    int*            bucket = (int*)p;

    // 1) cnt = 0 (must precede bucket atomics)
    zero_cnt_kernel<<<(n + 255) / 256, 256, 0, stream>>>(cnt, n);
    // 2) gemm-blocks || bucket-blocks in one dispatch
    mega_kernel<<<TOTAL_BLOCKS, 256, 0, stream>>>(x, w, ei, y, cnt, bucket, n, nE);
    // 3) gather
    gather_kernel<<<(n + 1) / 2, 128, 0, stream>>>(cnt, bucket, y, bias, out, n);
}